// Round 11
// baseline (2340.554 us; speedup 1.0000x reference)
//
#include <hip/hip_runtime.h>

// ---------------------------------------------------------------------------
// 2-layer Elman RNN LM forward on MI355X — overlap edition v5.
// Pre: Wih0/Wfc transposes, embed, U0 GEMM.
// k_mega (512 WGs x 256 thr, __launch_bounds__(256,1), ~180 VGPR -> 2 blk/CU
// -> ALL 512 blocks co-resident -> gating deadlock-free):
//   WG 0-15 : rec layer0 (cooperative-gather tag-in-data, R9 protocol)
//   WG 16-47: rec layer1 (+ agent-scope FEATS stores; vmcnt-ordered gprog)
//   WG 48-511: workers — work-steal logits tiles in t-phase order:
//              3 phases x 128-row tiles (gates 128/256/384) + 2 phases x
//              64-row tiles (gates 448/512). Logits stored NON-TEMPORAL so
//              the 824 MB stream doesn't evict WfcT from LLC.
// Post: partial-combine -> rowloss -> mean loss.
// ---------------------------------------------------------------------------

#define H_DIM 1024
#define B_SZ 8
#define T_SZ 512
#define V_SZ 50257
#define V_PAD 50304
#define NT128 9432     // 3 phases x 393 nb x 8 b (128-row tiles)
#define NTILES 15720   // + 2 phases x 3144 (64-row tiles)

typedef __attribute__((ext_vector_type(8))) short bf16x8;
typedef __attribute__((ext_vector_type(4))) float f32x4;

__device__ __forceinline__ unsigned short f2bf(float f) {
  unsigned int u = __float_as_uint(f);
  u += 0x7fffu + ((u >> 16) & 1u);   // round-to-nearest-even
  return (unsigned short)(u >> 16);
}
__device__ __forceinline__ float bf2f(unsigned short h) {
  return __uint_as_float(((unsigned int)h) << 16);
}
__device__ __forceinline__ float ftanh(float x) {
  float e = __expf(2.f * x);
  return 1.f - 2.f / (e + 1.f);
}
__device__ __forceinline__ int aload32(const int* p) {
  return __hip_atomic_load(p, __ATOMIC_RELAXED, __HIP_MEMORY_SCOPE_AGENT);
}
__device__ __forceinline__ void astore32(unsigned int* p, unsigned int v) {
  __hip_atomic_store(p, v, __ATOMIC_RELAXED, __HIP_MEMORY_SCOPE_AGENT);
}
__device__ __forceinline__ void astore32i(int* p, int v) {
  __hip_atomic_store(p, v, __ATOMIC_RELAXED, __HIP_MEMORY_SCOPE_AGENT);
}
__device__ __forceinline__ unsigned long long aload64(const void* p) {
  return __hip_atomic_load((const unsigned long long*)p, __ATOMIC_RELAXED,
                           __HIP_MEMORY_SCOPE_AGENT);
}
__device__ __forceinline__ void astore64(void* p, unsigned long long v) {
  __hip_atomic_store((unsigned long long*)p, v, __ATOMIC_RELAXED,
                     __HIP_MEMORY_SCOPE_AGENT);
}
__device__ __forceinline__ void gload_lds16(const void* g, void* l) {
  __builtin_amdgcn_global_load_lds(
      (const __attribute__((address_space(1))) void*)g,
      (__attribute__((address_space(3))) void*)l, 16, 0, 0);
}

// ---------------- transpose f32 [K][N] -> bf16 [Npad][K] --------------------
__global__ __launch_bounds__(256) void k_transpose(
    const float* __restrict__ in, unsigned short* __restrict__ out,
    int K, int N, int Npad)
{
  __shared__ float tile[32][33];
  const int n0 = blockIdx.x * 32, k0 = blockIdx.y * 32;
  const int tx = threadIdx.x, ty = threadIdx.y;
#pragma unroll
  for (int jj = 0; jj < 4; ++jj) {
    int k = k0 + ty + jj * 8, n = n0 + tx;
    tile[ty + jj * 8][tx] = (n < N) ? in[(size_t)k * N + n] : 0.f;
  }
  __syncthreads();
#pragma unroll
  for (int jj = 0; jj < 4; ++jj) {
    int n = n0 + ty + jj * 8, k = k0 + tx;
    if (n < Npad) out[(size_t)n * K + k] = f2bf((n < N) ? tile[tx][ty + jj * 8] : 0.f);
  }
}

// ---------------- embedding gather -> time-major bf16 [T*B][512] ------------
__global__ __launch_bounds__(128) void k_embed(
    const int* __restrict__ x, const float* __restrict__ E,
    unsigned short* __restrict__ xe)
{
  const int r = blockIdx.x;            // time-major row t*8+b
  const int t = r >> 3, b = r & 7;
  const int tok = x[b * T_SZ + t];
  const float4 v = ((const float4*)(E + (size_t)tok * 512))[threadIdx.x];
  ushort4 o;
  o.x = f2bf(v.x); o.y = f2bf(v.y); o.z = f2bf(v.z); o.w = f2bf(v.w);
  *((ushort4*)(xe + (size_t)r * 512) + threadIdx.x) = o;
}

// ---------------- bf16 MFMA GEMM (U0): C = A @ Bt^T -------------------------
template <bool BF16_OUT, bool BIAS>
__global__ __launch_bounds__(256) void k_gemm(
    const unsigned short* __restrict__ A, const unsigned short* __restrict__ Bt,
    void* __restrict__ Cout, const float* __restrict__ bias,
    int Nvalid, int K, int lda, int ldb, int ldc)
{
  __shared__ unsigned short As[8192];
  __shared__ unsigned short Bs[8192];
  const int tid = threadIdx.x;
  const int n0 = blockIdx.x * 128;
  const int m0 = blockIdx.y * 128;
  const int lane = tid & 63;
  const int wv = tid >> 6;
  const int wm = wv >> 1, wn = wv & 1;
  const int ln = lane & 15, cc = lane >> 4;
  f32x4 acc[4][4] = {};
  const int rr = tid >> 3;
  const int cb = (tid & 7) << 4;

  for (int kb = 0; kb < K; kb += 64) {
    __syncthreads();
#pragma unroll
    for (int is = 0; is < 4; ++is) {
      int r = is * 32 + rr;
      int sb = cb ^ ((r & 7) << 4);
      gload_lds16((const char*)(A + (size_t)(m0 + r) * lda + kb) + sb,
                  &As[(is * 32 + 8 * wv) * 64]);
    }
#pragma unroll
    for (int is = 0; is < 4; ++is) {
      int r = is * 32 + rr;
      int sb = cb ^ ((r & 7) << 4);
      gload_lds16((const char*)(Bt + (size_t)(n0 + r) * ldb + kb) + sb,
                  &Bs[(is * 32 + 8 * wv) * 64]);
    }
    __syncthreads();
#pragma unroll
    for (int kk = 0; kk < 2; ++kk) {
      bf16x8 af[4], bfr[4];
      const int kslot = kk * 64 + cc * 16;
#pragma unroll
      for (int mi = 0; mi < 4; ++mi) {
        int ra = wm * 64 + mi * 16 + ln;
        af[mi] = *(const bf16x8*)((const char*)As + ra * 128 + (kslot ^ ((ra & 7) << 4)));
      }
#pragma unroll
      for (int ni = 0; ni < 4; ++ni) {
        int rb = wn * 64 + ni * 16 + ln;
        bfr[ni] = *(const bf16x8*)((const char*)Bs + rb * 128 + (kslot ^ ((rb & 7) << 4)));
      }
#pragma unroll
      for (int mi = 0; mi < 4; ++mi)
#pragma unroll
        for (int ni = 0; ni < 4; ++ni)
          acc[mi][ni] = __builtin_amdgcn_mfma_f32_16x16x32_bf16(af[mi], bfr[ni], acc[mi][ni], 0, 0, 0);
    }
  }
#pragma unroll
  for (int ni = 0; ni < 4; ++ni) {
    const int col = n0 + wn * 64 + ni * 16 + ln;
    const bool cok = col < Nvalid;
    float bv = 0.f;
    if (BIAS && cok) bv = bias[col];
#pragma unroll
    for (int mi = 0; mi < 4; ++mi) {
#pragma unroll
      for (int i = 0; i < 4; ++i) {
        if (cok) {
          const int rowg = m0 + wm * 64 + mi * 16 + cc * 4 + i;
          if (BF16_OUT)
            ((unsigned short*)Cout)[(size_t)rowg * ldc + col] = f2bf(acc[mi][ni][i]);
          else
            ((float*)Cout)[(size_t)rowg * ldc + col] = acc[mi][ni][i] + bv;
        }
      }
    }
  }
}

// ---------------- tag-in-data recurrence (R9 protocol) ----------------------
template <int NQ>
__device__ __forceinline__ void gatherN(const uint2* __restrict__ sl,
    unsigned want, char* __restrict__ lds, int lane, int rowoff)
{
  unsigned long long v[NQ];
  for (;;) {
    bool ok = true;
#pragma unroll
    for (int q = 0; q < NQ; ++q)
      v[q] = aload64(sl + q * 64 + lane);
#pragma unroll
    for (int q = 0; q < NQ; ++q)
      ok &= ((unsigned)v[q] == want);
    if (__all(ok)) break;
  }
#pragma unroll
  for (int q = 0; q < NQ; ++q) {
    const int j = q * 64 + lane;
    const int row = rowoff + (j >> 9), kp = j & 511;
    *(unsigned*)(lds + ((row * 2048 + kp * 4) ^ ((row & 7) << 4))) =
        (unsigned)(v[q] >> 32);
  }
}

__device__ __forceinline__ void load_bw(bf16x8* bw, const float* W, int cc, int col)
{
#pragma unroll
  for (int kc = 0; kc < 32; ++kc) {
    const float* wp = W + (size_t)(kc * 32 + cc * 8) * H_DIM + col;
    bf16x8 v;
#pragma unroll
    for (int q = 0; q < 8; ++q) v[q] = (short)f2bf(wp[(size_t)q * H_DIM]);
    bw[kc] = v;
  }
}

__device__ __forceinline__ f32x4 mfma_k1024(const char* hs, const bf16x8* bw,
                                            int cc, int r)
{
  f32x4 ac0 = {}, ac1 = {};
  const int swz = r << 4;
#pragma unroll
  for (int kc = 0; kc < 32; kc += 2) {
    bf16x8 a0 = *(const bf16x8*)(hs + r * 2048 + ((kc * 64 + cc * 16) ^ swz));
    bf16x8 a1 = *(const bf16x8*)(hs + r * 2048 + (((kc + 1) * 64 + cc * 16) ^ swz));
    ac0 = __builtin_amdgcn_mfma_f32_16x16x32_bf16(a0, bw[kc], ac0, 0, 0, 0);
    ac1 = __builtin_amdgcn_mfma_f32_16x16x32_bf16(a1, bw[kc + 1], ac1, 0, 0, 0);
  }
  return ac0 + ac1;
}

// layer 0: WG owns 64 cols; 4 waves share one h0 stage (16 loads/lane).
__device__ void rec0(const unsigned short* U0, const float* Whh0,
    uint2* h0ring, const int* prog, char* smem, int wg)
{
  __builtin_amdgcn_s_setprio(1);
  const int tid = threadIdx.x, lane = tid & 63, wv = tid >> 6;
  const int ln = lane & 15, cc = lane >> 4, r = ln & 7;
  const int col = wg * 64 + wv * 16 + ln;
  char* stage = smem;
  bf16x8 bw[32];
  load_bw(bw, Whh0, cc, col);
#pragma unroll 1
  for (int t = 0; t < T_SZ; ++t) {
    unsigned short uva[4] = {0, 0, 0, 0};
    if (cc < 2) {
#pragma unroll
      for (int i = 0; i < 4; ++i)
        uva[i] = U0[(size_t)(t * B_SZ + cc * 4 + i) * H_DIM + col];
    }
    gatherN<16>(h0ring + ((t + 3) & 3) * 4096 + wv * 1024, (unsigned)t,
                stage, lane, wv * 2);
    __syncthreads();                   // B1: stage complete
    f32x4 ac = mfma_k1024(stage, bw, cc, r);
    __syncthreads();                   // B2: all stage reads done
    float hv[4] = {0.f, 0.f, 0.f, 0.f};
    if (cc < 2) {
#pragma unroll
      for (int i = 0; i < 4; ++i) hv[i] = ftanh(ac[i] + bf2f(uva[i]));
    }
    unsigned wpk[4];
#pragma unroll
    for (int i = 0; i < 4; ++i) {
      float pv = __shfl_xor(hv[i], 1);
      wpk[i] = (unsigned)f2bf(hv[i]) | ((unsigned)f2bf(pv) << 16);
    }
    if (t >= 4) {                      // h0[t] overwrites h0[t-4]
      const int* pp = prog + (lane & 31);
      while (!__all(aload32(pp) >= t - 3)) __builtin_amdgcn_s_sleep(1);
    }
    if (cc < 2 && !(ln & 1)) {
      uint2* outs = h0ring + (t & 3) * 4096;
      const int kp = col >> 1;
#pragma unroll
      for (int i = 0; i < 4; ++i)
        astore64(outs + (cc * 4 + i) * 512 + kp,
                 ((unsigned long long)wpk[i] << 32) | (unsigned long long)(t + 1));
    }
  }
}

// layer 1: WG owns 32 cols; waves 0/1 = A (Wih1), waves 2/3 = B (Whh1 + out).
__device__ void rec1(const float* Wih1, const float* Whh1,
    unsigned short* feats, uint2* h0ring, uint2* h1ring, int* prog,
    int* gprog, char* smem, int wg)
{
  __builtin_amdgcn_s_setprio(1);
  const int tid = threadIdx.x, lane = tid & 63, wv = tid >> 6;
  const int ln = lane & 15, cc = lane >> 4, r = ln & 7;
  const int isB = wv >> 1;
  const int half = wv & 1;
  const int col = wg * 32 + half * 16 + ln;
  char* h0s = smem;
  char* h1s = smem + 16384;
  float* part = (float*)(smem + 32768);
  bf16x8 bw[32];
  load_bw(bw, isB ? Whh1 : Wih1, cc, col);
#pragma unroll 1
  for (int t = 0; t < T_SZ; ++t) {
    const uint2* ring = isB ? (h1ring + ((t + 3) & 3) * 4096)
                            : (h0ring + (t & 3) * 4096);
    char* stg = isB ? h1s : h0s;
    gatherN<32>(ring + half * 2048, (unsigned)(isB ? t : t + 1),
                stg, lane, half * 4);
    __syncthreads();                   // B1
    f32x4 ac = mfma_k1024(isB ? h1s : h0s, bw, cc, r);
    if (!isB) *(f32x4*)(part + half * 256 + lane * 4) = ac;
    __syncthreads();                   // B2
    if (isB) {
      f32x4 pa = *(const f32x4*)(part + half * 256 + lane * 4);
      float hv[4] = {0.f, 0.f, 0.f, 0.f};
      if (cc < 2) {
#pragma unroll
        for (int i = 0; i < 4; ++i) hv[i] = ftanh(ac[i] + pa[i]);
      }
      unsigned wpk[4];
#pragma unroll
      for (int i = 0; i < 4; ++i) {
        float pv = __shfl_xor(hv[i], 1);
        wpk[i] = (unsigned)f2bf(hv[i]) | ((unsigned)f2bf(pv) << 16);
      }
      if (cc < 2 && !(ln & 1)) {
        uint2* outs = h1ring + (t & 3) * 4096;
        const int kp = col >> 1;
#pragma unroll
        for (int i = 0; i < 4; ++i) {
          astore64(outs + (cc * 4 + i) * 512 + kp,
                   ((unsigned long long)wpk[i] << 32) | (unsigned long long)(t + 1));
          astore32((unsigned*)(feats + (size_t)(cc * 4 + i) * 524288 +
                               (size_t)t * 1024 + col), wpk[i]);
        }
      }
      if ((t & 7) == 7) {              // ordered worker gate, 8-tick gran
        asm volatile("s_waitcnt vmcnt(0)" ::: "memory");
        if (lane == 0) astore32i(gprog + (wg * 2 + half) * 32, t + 1);
      }
    }
    if (wv == 2 && lane == 0) astore32i(prog + wg, t + 1);  // L0 backpressure
  }
}

// ---------------- worker: gated 128x128 logits tile + lse partials ----------
__device__ void gemm_tile(const unsigned short* __restrict__ A,
    const unsigned short* __restrict__ Bt, float* __restrict__ C,
    const float* __restrict__ bias, float2* __restrict__ PARTg,
    char* smem, int m0, int nb)
{
  unsigned short* As = (unsigned short*)smem;
  unsigned short* Bs = (unsigned short*)(smem + 16384);
  float2* lpart = (float2*)(smem + 32768);
  const int n0 = nb * 128;
  const int tid = threadIdx.x;
  const int lane = tid & 63;
  const int wv = tid >> 6;
  const int wm = wv >> 1, wn = wv & 1;
  const int ln = lane & 15, cc = lane >> 4;
  f32x4 acc[4][4] = {};
  const int rr = tid >> 3;
  const int cb = (tid & 7) << 4;

  for (int kb = 0; kb < H_DIM; kb += 64) {
    __syncthreads();
#pragma unroll
    for (int is = 0; is < 4; ++is) {
      int r = is * 32 + rr;
      int sb = cb ^ ((r & 7) << 4);
      gload_lds16((const char*)(A + (size_t)(m0 + r) * H_DIM + kb) + sb,
                  &As[(is * 32 + 8 * wv) * 64]);
    }
#pragma unroll
    for (int is = 0; is < 4; ++is) {
      int r = is * 32 + rr;
      int sb = cb ^ ((r & 7) << 4);
      gload_lds16((const char*)(Bt + (size_t)(n0 + r) * H_DIM + kb) + sb,
                  &Bs[(is * 32 + 8 * wv) * 64]);
    }
    __syncthreads();
#pragma unroll
    for (int kk = 0; kk < 2; ++kk) {
      bf16x8 af[4], bfr[4];
      const int kslot = kk * 64 + cc * 16;
#pragma unroll
      for (int mi = 0; mi < 4; ++mi) {
        int ra = wm * 64 + mi * 16 + ln;
        af[mi] = *(const bf16x8*)((const char*)As + ra * 128 + (kslot ^ ((ra & 7) << 4)));
      }
#pragma unroll
      for (int ni = 0; ni < 4; ++ni) {
        int rb = wn * 64 + ni * 16 + ln;
        bfr[ni] = *(const bf16x8*)((const char*)Bs + rb * 128 + (kslot ^ ((rb & 7) << 4)));
      }
#pragma unroll
      for (int mi = 0; mi < 4; ++mi)
#pragma unroll
        for (int ni = 0; ni < 4; ++ni)
          acc[mi][ni] = __builtin_amdgcn_mfma_f32_16x16x32_bf16(af[mi], bfr[ni], acc[mi][ni], 0, 0, 0);
    }
  }
  float bvn[4]; int ckn[4];
#pragma unroll
  for (int ni = 0; ni < 4; ++ni) {
    int col = n0 + wn * 64 + ni * 16 + ln;
    ckn[ni] = col < V_SZ;
    bvn[ni] = ckn[ni] ? bias[col] : 0.f;
  }
  float fm[16], fs[16];
#pragma unroll
  for (int mi = 0; mi < 4; ++mi) {
#pragma unroll
    for (int i = 0; i < 4; ++i) {
      float v[4];
#pragma unroll
      for (int ni = 0; ni < 4; ++ni) {
        float tv = acc[mi][ni][i] + bvn[ni];
        v[ni] = ckn[ni] ? tv : -1e30f;
        if (ckn[ni]) {
          int col = n0 + wn * 64 + ni * 16 + ln;
          __builtin_nontemporal_store(tv,
              &C[(size_t)(m0 + wm * 64 + mi * 16 + cc * 4 + i) * V_SZ + col]);
        }
      }
      float mx = fmaxf(fmaxf(v[0], v[1]), fmaxf(v[2], v[3]));
#pragma unroll
      for (int m = 1; m < 16; m <<= 1) mx = fmaxf(mx, __shfl_xor(mx, m));
      float se = __expf(v[0] - mx) + __expf(v[1] - mx) +
                 __expf(v[2] - mx) + __expf(v[3] - mx);
#pragma unroll
      for (int m = 1; m < 16; m <<= 1) se += __shfl_xor(se, m);
      fm[mi * 4 + i] = mx; fs[mi * 4 + i] = se;
    }
  }
  if (wn == 0 && ln == 0) {
#pragma unroll
    for (int mi = 0; mi < 4; ++mi)
#pragma unroll
      for (int i = 0; i < 4; ++i) {
        int rl = wm * 64 + mi * 16 + cc * 4 + i;
        lpart[rl] = make_float2(fm[mi * 4 + i], fs[mi * 4 + i]);
      }
  }
  __syncthreads();
  if (wn == 1 && ln == 0) {
#pragma unroll
    for (int mi = 0; mi < 4; ++mi)
#pragma unroll
      for (int i = 0; i < 4; ++i) {
        int rl = wm * 64 + mi * 16 + cc * 4 + i;
        float2 o = lpart[rl];
        float mx = fm[mi * 4 + i], se = fs[mi * 4 + i];
        float nm = fmaxf(mx, o.x);
        float S = se * __expf(mx - nm) + o.y * __expf(o.x - nm);
        PARTg[(size_t)(m0 + rl) * 393 + nb] = make_float2(nm, S);
      }
  }
}

// 64-row x 128-col tile: 4 waves, wave wv owns cols n0+wv*32..+31.
__device__ void gemm_tile64(const unsigned short* __restrict__ A,
    const unsigned short* __restrict__ Bt, float* __restrict__ C,
    const float* __restrict__ bias, float2* __restrict__ PARTg,
    char* smem, int m0, int nb)
{
  unsigned short* As = (unsigned short*)smem;            // 64 x 64 (8 KB)
  unsigned short* Bs = (unsigned short*)(smem + 16384);  // 128 x 64 (16 KB)
  float2* lpart4 = (float2*)(smem + 32768);              // 4 x 64 rows (2 KB)
  const int n0 = nb * 128;
  const int tid = threadIdx.x;
  const int lane = tid & 63;
  const int wv = tid >> 6;
  const int ln = lane & 15, cc = lane >> 4;
  f32x4 acc[4][2] = {};
  const int rr = tid >> 3;
  const int cb = (tid & 7) << 4;

  for (int kb = 0; kb < H_DIM; kb += 64) {
    __syncthreads();
#pragma unroll
    for (int is = 0; is < 2; ++is) {
      int r = is * 32 + rr;
      int sb = cb ^ ((r & 7) << 4);
      gload_lds16((const char*)(A + (size_t)(m0 + r) * H_DIM + kb) + sb,
                  &As[(is * 32 + 8 * wv) * 64]);
    }
#pragma unroll
    for (int is = 0; is < 4; ++is) {
      int r = is * 32 + rr;
      int sb = cb ^ ((r & 7) << 4);
      gload_lds16((const char*)(Bt + (size_t)(n0 + r) * H_DIM + kb) + sb,
                  &Bs[(is * 32 + 8 * wv) * 64]);
    }
    __syncthreads();
#pragma unroll
    for (int kk = 0; kk < 2; ++kk) {
      bf16x8 af[4], bfr[2];
      const int kslot = kk * 64 + cc * 16;
#pragma unroll
      for (int mi = 0; mi < 4; ++mi) {
        int ra = mi * 16 + ln;
        af[mi] = *(const bf16x8*)((const char*)As + ra * 128 + (kslot ^ ((ra & 7) << 4)));
      }
#pragma unroll
      for (int ni = 0; ni < 2; ++ni) {
        int rb = wv * 32 + ni * 16 + ln;
        bfr[ni] = *(const bf16x8*)((const char*)Bs + rb * 128 + (kslot ^ ((rb & 7) << 4)));
      }
#pragma unroll
      for (int mi = 0; mi < 4; ++mi)
#pragma unroll
        for (int ni = 0; ni < 2; ++ni)
          acc[mi][ni] = __builtin_amdgcn_mfma_f32_16x16x32_bf16(af[mi], bfr[ni], acc[mi][ni], 0, 0, 0);
    }
  }
  float bvn[2]; int ckn[2];
#pragma unroll
  for (int ni = 0; ni < 2; ++ni) {
    int col = n0 + wv * 32 + ni * 16 + ln;
    ckn[ni] = col < V_SZ;
    bvn[ni] = ckn[ni] ? bias[col] : 0.f;
  }
  float fm[16], fs[16];
#pragma unroll
  for (int mi = 0; mi < 4; ++mi) {
#pragma unroll
    for (int i = 0; i < 4; ++i) {
      float v[2];
#pragma unroll
      for (int ni = 0; ni < 2; ++ni) {
        float tv = acc[mi][ni][i] + bvn[ni];
        v[ni] = ckn[ni] ? tv : -1e30f;
        if (ckn[ni]) {
          int col = n0 + wv * 32 + ni * 16 + ln;
          __builtin_nontemporal_store(tv,
              &C[(size_t)(m0 + mi * 16 + cc * 4 + i) * V_SZ + col]);
        }
      }
      float mx = fmaxf(v[0], v[1]);
#pragma unroll
      for (int m = 1; m < 16; m <<= 1) mx = fmaxf(mx, __shfl_xor(mx, m));
      float se = __expf(v[0] - mx) + __expf(v[1] - mx);
#pragma unroll
      for (int m = 1; m < 16; m <<= 1) se += __shfl_xor(se, m);
      fm[mi * 4 + i] = mx; fs[mi * 4 + i] = se;
    }
  }
  if (ln == 0) {
#pragma unroll
    for (int mi = 0; mi < 4; ++mi)
#pragma unroll
      for (int i = 0; i < 4; ++i)
        lpart4[wv * 64 + mi * 16 + cc * 4 + i] =
            make_float2(fm[mi * 4 + i], fs[mi * 4 + i]);
  }
  __syncthreads();
  if (tid < 64) {
    float2 a = lpart4[tid];
#pragma unroll
    for (int w = 1; w < 4; ++w) {
      float2 o = lpart4[w * 64 + tid];
      float nm = fmaxf(a.x, o.x);
      a.y = a.y * __expf(a.x - nm) + o.y * __expf(o.x - nm);
      a.x = nm;
    }
    PARTg[(size_t)(m0 + tid) * 393 + nb] = a;
  }
}

__device__ void worker_body(const unsigned short* FEATS,
    const unsigned short* WfcT, const float* bias, float* C, float2* PARTg,
    const int* gprog, int* TILE, char* smem)
{
  const int tid = threadIdx.x;
  int* sT = (int*)(smem + 34816);
  int passed = 0;
  for (;;) {
    __syncthreads();
    if (tid == 0)
      *sT = __hip_atomic_fetch_add(TILE, 1, __ATOMIC_RELAXED, __HIP_MEMORY_SCOPE_AGENT);
    __syncthreads();
    int id = *sT;
    if (id >= NTILES) break;
    int m0, thr, nb, rows;
    if (id < NT128) {
      int p = id / 3144, rem = id % 3144, b = rem % 8;
      nb = rem / 8;
      m0 = b * 512 + p * 128;
      thr = 128 * (p + 1);
      rows = 128;
    } else {
      int q = id - NT128;
      int p = q / 3144, rem = q % 3144, b = rem % 8;
      nb = rem / 8;
      m0 = b * 512 + 384 + p * 64;
      thr = 448 + p * 64;
      rows = 64;
    }
    if (thr > passed) {
      const int lane = tid & 63;
      const int* gp = gprog + lane * 32;
      while (!__all(aload32(gp) >= thr)) __builtin_amdgcn_s_sleep(32);
      passed = thr;
    }
    if (rows == 128) gemm_tile(FEATS, WfcT, C, bias, PARTg, smem, m0, nb);
    else gemm_tile64(FEATS, WfcT, C, bias, PARTg, smem, m0, nb);
  }
}

// ---------------- mega kernel ----------------------------------------------
__global__ __launch_bounds__(256, 1) void k_mega(
    const unsigned short* __restrict__ U0, const float* __restrict__ Whh0,
    const float* __restrict__ Wih1, const float* __restrict__ Whh1,
    unsigned short* __restrict__ FEATS, const unsigned short* __restrict__ WfcT,
    const float* __restrict__ bfc, float* __restrict__ logits,
    float2* __restrict__ PART, uint2* __restrict__ h0ring,
    uint2* __restrict__ h1ring, int* __restrict__ prog,
    int* __restrict__ gprog, int* __restrict__ TILE)
{
  __shared__ __align__(16) char smem[35840];
  const int bid = blockIdx.x;
  if (bid < 16)
    rec0(U0, Whh0, h0ring, prog, smem, bid);
  else if (bid < 48)
    rec1(Wih1, Whh1, FEATS, h0ring, h1ring, prog, gprog, smem, bid - 16);
  else
    worker_body(FEATS, WfcT, bfc, logits, PART, gprog, TILE, smem);
}

// ---------------- loss: combine per-tile partials ---------------------------
__global__ __launch_bounds__(64) void k_loss_combine(
    const float2* __restrict__ PARTg, const float* __restrict__ logits,
    const int* __restrict__ y, float* __restrict__ rowloss)
{
  const int row = blockIdx.x, l = threadIdx.x;
  float M = -1e30f, S = 0.f;
  for (int i = l; i < 393; i += 64) {
    float2 p = PARTg[(size_t)row * 393 + i];
    float nm = fmaxf(M, p.x);
    S = S * __expf(M - nm) + p.y * __expf(p.x - nm);
    M = nm;
  }
#pragma unroll
  for (int off = 32; off > 0; off >>= 1) {
    float mo = __shfl_xor(M, off), so = __shfl_xor(S, off);
    float nm = fmaxf(M, mo);
    S = S * __expf(M - nm) + so * __expf(mo - nm);
    M = nm;
  }
  if (l == 0) {
    int tgt = y[row];
    float r = 0.f;
    if (tgt >= 0) r = M + __logf(S) - logits[(size_t)row * V_SZ + tgt];
    rowloss[row] = r;
  }
}

__global__ __launch_bounds__(256) void k_loss_final(
    const float* __restrict__ rowloss, const int* __restrict__ y,
    float* __restrict__ out)
{
  const int tid = threadIdx.x;
  float s = 0.f, c = 0.f;
  for (int i = tid; i < B_SZ * T_SZ; i += 256) {
    if (y[i] != -1) { s += rowloss[i]; c += 1.f; }
  }
  for (int off = 32; off > 0; off >>= 1) { s += __shfl_xor(s, off); c += __shfl_xor(c, off); }
  __shared__ float as_[4], ac_[4];
  const int wvi = tid >> 6, lnn = tid & 63;
  if (lnn == 0) { as_[wvi] = s; ac_[wvi] = c; }
  __syncthreads();
  if (tid == 0) {
    float S = as_[0] + as_[1] + as_[2] + as_[3];
    float C = ac_[0] + ac_[1] + ac_[2] + ac_[3];
    out[0] = S / fmaxf(C, 1.f);
  }
}

// ---------------- launch ----------------------------------------------------
extern "C" void kernel_launch(void* const* d_in, const int* in_sizes, int n_in,
                              void* d_out, int out_size, void* d_ws, size_t ws_size,
                              hipStream_t stream) {
  (void)in_sizes; (void)n_in; (void)ws_size;
  const int* x = (const int*)d_in[0];
  const int* y = (const int*)d_in[1];
  const float* E = (const float*)d_in[2];
  const float* Wih0 = (const float*)d_in[3];
  const float* Whh0 = (const float*)d_in[4];
  const float* Wih1 = (const float*)d_in[5];
  const float* Whh1 = (const float*)d_in[6];
  const float* Wfc = (const float*)d_in[7];
  const float* bfc = (const float*)d_in[8];
  char* ws = (char*)d_ws;
  // workspace layout (bytes)
  unsigned short* WfcT  = (unsigned short*)(ws + 0ULL);            // 103,022,592
  unsigned short* Wih0T = (unsigned short*)(ws + 103022592ULL);    // 1,048,576
  unsigned short* XE    = (unsigned short*)(ws + 104071168ULL);    // 4,194,304
  unsigned short* U0    = (unsigned short*)(ws + 108265472ULL);    // 8,388,608
  unsigned short* FEATS = (unsigned short*)(ws + 116654080ULL);    // 8,388,608
  float2* PART          = (float2*)(ws + 125042688ULL);            // 12,877,824
  float* ROWLOSS        = (float*)(ws + 137920512ULL);             // 16,384
  uint2* H0R            = (uint2*)(ws + 137936896ULL);             // 131,072
  uint2* H1R            = (uint2*)(ws + 138067968ULL);             // 131,072
  int* PROG             = (int*)(ws + 138199040ULL);               // 256
  int* GPROG            = (int*)(ws + 138199296ULL);               // 8,192
  int* TILE             = (int*)(ws + 138207488ULL);               // 256
  float* logits = (float*)d_out;
  float* lossp = logits + (size_t)(out_size - 1);

  // zero h rings (tags = 0 == "h[-1] ready") + prog/gprog/tile, every replay
  hipMemsetAsync(ws + 137936896ULL, 0, 270848, stream);

  // pre: weight transposes, embed, U0 GEMM
  k_transpose<<<dim3(32, 16), dim3(32, 8), 0, stream>>>(Wih0, Wih0T, 512, 1024, 1024);
  k_transpose<<<dim3(1572, 32), dim3(32, 8), 0, stream>>>(Wfc, WfcT, 1024, V_SZ, V_PAD);
  k_embed<<<4096, 128, 0, stream>>>(x, E, XE);
  k_gemm<true, false><<<dim3(8, 32), 256, 0, stream>>>(XE, Wih0T, U0, nullptr,
                                                       1024, 512, 512, 512, 1024);
  // mega: rec L0+L1 + overlapped gated logits GEMM (NT stores) + lse partials
  k_mega<<<512, 256, 0, stream>>>(U0, Whh0, Wih1, Whh1, FEATS, WfcT, bfc,
                                  logits, PART, H0R, H1R, PROG, GPROG, TILE);
  // loss
  k_loss_combine<<<4096, 64, 0, stream>>>(PART, logits, y, ROWLOSS);
  k_loss_final<<<1, 256, 0, stream>>>(ROWLOSS, y, lossp);
}

// Round 13
// 2174.520 us; speedup vs baseline: 1.0764x; 1.0764x over previous
//
#include <hip/hip_runtime.h>

// ---------------------------------------------------------------------------
// 2-layer Elman RNN LM forward on MI355X — overlap edition v6b (512-thr).
// Pre: Wih0 transpose, embed, U0 GEMM.
// k_mega (256 WGs x 512 thr, __launch_bounds__(512) -> VGPR<=256 -> 1 blk/CU
// -> ALL co-resident; rec WGs on private CUs):
//   WG 0-7  : rec layer0 (8 waves, 128 cols/WG, 8 gather loads/lane)
//   WG 8-23 : rec layer1 (8 waves: 4A=Wih1 + 4B=Whh1; 8+8 loads/lane)
//   WG 24-255: workers — phase A: work-steal WfcT transpose chunks; phase B:
//             work-steal 12576 logits 128x128 tiles gated on gprog
//             (vmcnt-ordered, 8-tick); NT logits stores + fused lse partials.
// Post: partial-combine -> rowloss -> mean loss.
// R12 crash fixes: TILE counter now inside the zeroed CNT region (1 KB);
// launch_bounds(512) without min-waves arg (launchability-guaranteed cap).
// ---------------------------------------------------------------------------

#define H_DIM 1024
#define B_SZ 8
#define T_SZ 512
#define V_SZ 50257
#define V_PAD 50304
#define NCHUNK 1572
#define NWORKER 232
#define NTILES 12576   // 4 phases x 393 nb x 8 b

typedef __attribute__((ext_vector_type(8))) short bf16x8;
typedef __attribute__((ext_vector_type(4))) float f32x4;

__device__ __forceinline__ unsigned short f2bf(float f) {
  unsigned int u = __float_as_uint(f);
  u += 0x7fffu + ((u >> 16) & 1u);   // round-to-nearest-even
  return (unsigned short)(u >> 16);
}
__device__ __forceinline__ float bf2f(unsigned short h) {
  return __uint_as_float(((unsigned int)h) << 16);
}
__device__ __forceinline__ float ftanh(float x) {
  float e = __expf(2.f * x);
  return 1.f - 2.f / (e + 1.f);
}
__device__ __forceinline__ int aload32(const int* p) {
  return __hip_atomic_load(p, __ATOMIC_RELAXED, __HIP_MEMORY_SCOPE_AGENT);
}
__device__ __forceinline__ void astore32(unsigned int* p, unsigned int v) {
  __hip_atomic_store(p, v, __ATOMIC_RELAXED, __HIP_MEMORY_SCOPE_AGENT);
}
__device__ __forceinline__ void astore32i(int* p, int v) {
  __hip_atomic_store(p, v, __ATOMIC_RELAXED, __HIP_MEMORY_SCOPE_AGENT);
}
__device__ __forceinline__ unsigned long long aload64(const void* p) {
  return __hip_atomic_load((const unsigned long long*)p, __ATOMIC_RELAXED,
                           __HIP_MEMORY_SCOPE_AGENT);
}
__device__ __forceinline__ void astore64(void* p, unsigned long long v) {
  __hip_atomic_store((unsigned long long*)p, v, __ATOMIC_RELAXED,
                     __HIP_MEMORY_SCOPE_AGENT);
}
__device__ __forceinline__ void gload_lds16(const void* g, void* l) {
  __builtin_amdgcn_global_load_lds(
      (const __attribute__((address_space(1))) void*)g,
      (__attribute__((address_space(3))) void*)l, 16, 0, 0);
}

// ---------------- transpose f32 [K][N] -> bf16 [Npad][K] (pre, Wih0) -------
__global__ __launch_bounds__(256) void k_transpose(
    const float* __restrict__ in, unsigned short* __restrict__ out,
    int K, int N, int Npad)
{
  __shared__ float tile[32][33];
  const int n0 = blockIdx.x * 32, k0 = blockIdx.y * 32;
  const int tx = threadIdx.x, ty = threadIdx.y;
#pragma unroll
  for (int jj = 0; jj < 4; ++jj) {
    int k = k0 + ty + jj * 8, n = n0 + tx;
    tile[ty + jj * 8][tx] = (n < N) ? in[(size_t)k * N + n] : 0.f;
  }
  __syncthreads();
#pragma unroll
  for (int jj = 0; jj < 4; ++jj) {
    int n = n0 + ty + jj * 8, k = k0 + tx;
    if (n < Npad) out[(size_t)n * K + k] = f2bf((n < N) ? tile[tx][ty + jj * 8] : 0.f);
  }
}

// ---------------- embedding gather -> time-major bf16 [T*B][512] ------------
__global__ __launch_bounds__(128) void k_embed(
    const int* __restrict__ x, const float* __restrict__ E,
    unsigned short* __restrict__ xe)
{
  const int r = blockIdx.x;            // time-major row t*8+b
  const int t = r >> 3, b = r & 7;
  const int tok = x[b * T_SZ + t];
  const float4 v = ((const float4*)(E + (size_t)tok * 512))[threadIdx.x];
  ushort4 o;
  o.x = f2bf(v.x); o.y = f2bf(v.y); o.z = f2bf(v.z); o.w = f2bf(v.w);
  *((ushort4*)(xe + (size_t)r * 512) + threadIdx.x) = o;
}

// ---------------- bf16 MFMA GEMM (U0): C = A @ Bt^T -------------------------
template <bool BF16_OUT, bool BIAS>
__global__ __launch_bounds__(256) void k_gemm(
    const unsigned short* __restrict__ A, const unsigned short* __restrict__ Bt,
    void* __restrict__ Cout, const float* __restrict__ bias,
    int Nvalid, int K, int lda, int ldb, int ldc)
{
  __shared__ unsigned short As[8192];
  __shared__ unsigned short Bs[8192];
  const int tid = threadIdx.x;
  const int n0 = blockIdx.x * 128;
  const int m0 = blockIdx.y * 128;
  const int lane = tid & 63;
  const int wv = tid >> 6;
  const int wm = wv >> 1, wn = wv & 1;
  const int ln = lane & 15, cc = lane >> 4;
  f32x4 acc[4][4] = {};
  const int rr = tid >> 3;
  const int cb = (tid & 7) << 4;

  for (int kb = 0; kb < K; kb += 64) {
    __syncthreads();
#pragma unroll
    for (int is = 0; is < 4; ++is) {
      int r = is * 32 + rr;
      int sb = cb ^ ((r & 7) << 4);
      gload_lds16((const char*)(A + (size_t)(m0 + r) * lda + kb) + sb,
                  &As[(is * 32 + 8 * wv) * 64]);
    }
#pragma unroll
    for (int is = 0; is < 4; ++is) {
      int r = is * 32 + rr;
      int sb = cb ^ ((r & 7) << 4);
      gload_lds16((const char*)(Bt + (size_t)(n0 + r) * ldb + kb) + sb,
                  &Bs[(is * 32 + 8 * wv) * 64]);
    }
    __syncthreads();
#pragma unroll
    for (int kk = 0; kk < 2; ++kk) {
      bf16x8 af[4], bfr[4];
      const int kslot = kk * 64 + cc * 16;
#pragma unroll
      for (int mi = 0; mi < 4; ++mi) {
        int ra = wm * 64 + mi * 16 + ln;
        af[mi] = *(const bf16x8*)((const char*)As + ra * 128 + (kslot ^ ((ra & 7) << 4)));
      }
#pragma unroll
      for (int ni = 0; ni < 4; ++ni) {
        int rb = wn * 64 + ni * 16 + ln;
        bfr[ni] = *(const bf16x8*)((const char*)Bs + rb * 128 + (kslot ^ ((rb & 7) << 4)));
      }
#pragma unroll
      for (int mi = 0; mi < 4; ++mi)
#pragma unroll
        for (int ni = 0; ni < 4; ++ni)
          acc[mi][ni] = __builtin_amdgcn_mfma_f32_16x16x32_bf16(af[mi], bfr[ni], acc[mi][ni], 0, 0, 0);
    }
  }
#pragma unroll
  for (int ni = 0; ni < 4; ++ni) {
    const int col = n0 + wn * 64 + ni * 16 + ln;
    const bool cok = col < Nvalid;
    float bv = 0.f;
    if (BIAS && cok) bv = bias[col];
#pragma unroll
    for (int mi = 0; mi < 4; ++mi) {
#pragma unroll
      for (int i = 0; i < 4; ++i) {
        if (cok) {
          const int rowg = m0 + wm * 64 + mi * 16 + cc * 4 + i;
          if (BF16_OUT)
            ((unsigned short*)Cout)[(size_t)rowg * ldc + col] = f2bf(acc[mi][ni][i]);
          else
            ((float*)Cout)[(size_t)rowg * ldc + col] = acc[mi][ni][i] + bv;
        }
      }
    }
  }
}

// ---------------- tag-in-data recurrence (R9 protocol, 8-way split) ---------
template <int NQ>
__device__ __forceinline__ void gatherN(const uint2* __restrict__ sl,
    unsigned want, char* __restrict__ lds, int lane, int rowoff)
{
  unsigned long long v[NQ];
  for (;;) {
    bool ok = true;
#pragma unroll
    for (int q = 0; q < NQ; ++q)
      v[q] = aload64(sl + q * 64 + lane);
#pragma unroll
    for (int q = 0; q < NQ; ++q)
      ok &= ((unsigned)v[q] == want);
    if (__all(ok)) break;
  }
#pragma unroll
  for (int q = 0; q < NQ; ++q) {
    const int j = q * 64 + lane;
    const int row = rowoff + (j >> 9), kp = j & 511;
    *(unsigned*)(lds + ((row * 2048 + kp * 4) ^ ((row & 7) << 4))) =
        (unsigned)(v[q] >> 32);
  }
}

__device__ __forceinline__ void load_bw(bf16x8* bw, const float* W, int cc, int col)
{
#pragma unroll
  for (int kc = 0; kc < 32; ++kc) {
    const float* wp = W + (size_t)(kc * 32 + cc * 8) * H_DIM + col;
    bf16x8 v;
#pragma unroll
    for (int q = 0; q < 8; ++q) v[q] = (short)f2bf(wp[(size_t)q * H_DIM]);
    bw[kc] = v;
  }
}

__device__ __forceinline__ f32x4 mfma_k1024(const char* hs, const bf16x8* bw,
                                            int cc, int r)
{
  f32x4 ac0 = {}, ac1 = {};
  const int swz = r << 4;
#pragma unroll
  for (int kc = 0; kc < 32; kc += 2) {
    bf16x8 a0 = *(const bf16x8*)(hs + r * 2048 + ((kc * 64 + cc * 16) ^ swz));
    bf16x8 a1 = *(const bf16x8*)(hs + r * 2048 + (((kc + 1) * 64 + cc * 16) ^ swz));
    ac0 = __builtin_amdgcn_mfma_f32_16x16x32_bf16(a0, bw[kc], ac0, 0, 0, 0);
    ac1 = __builtin_amdgcn_mfma_f32_16x16x32_bf16(a1, bw[kc + 1], ac1, 0, 0, 0);
  }
  return ac0 + ac1;
}

// layer 0: WG owns 128 cols; 8 waves share one h0 stage (8 loads/lane).
__device__ void rec0(const unsigned short* U0, const float* Whh0,
    uint2* h0ring, const int* prog, char* smem, int wg)
{
  __builtin_amdgcn_s_setprio(1);
  const int tid = threadIdx.x, lane = tid & 63, wv = tid >> 6;  // wv 0..7
  const int ln = lane & 15, cc = lane >> 4, r = ln & 7;
  const int col = wg * 128 + wv * 16 + ln;
  char* stage = smem;                  // 16 KB shared h0 stage
  bf16x8 bw[32];
  load_bw(bw, Whh0, cc, col);
#pragma unroll 1
  for (int t = 0; t < T_SZ; ++t) {
    unsigned short uva[4] = {0, 0, 0, 0};
    if (cc < 2) {
#pragma unroll
      for (int i = 0; i < 4; ++i)
        uva[i] = U0[(size_t)(t * B_SZ + cc * 4 + i) * H_DIM + col];
    }
    // wave wv gathers row wv (512 slots = 8 loads/lane)
    gatherN<8>(h0ring + ((t + 3) & 3) * 4096 + wv * 512, (unsigned)t,
               stage, lane, wv);
    __syncthreads();                   // B1: stage complete
    f32x4 ac = mfma_k1024(stage, bw, cc, r);
    __syncthreads();                   // B2: all stage reads done
    float hv[4] = {0.f, 0.f, 0.f, 0.f};
    if (cc < 2) {
#pragma unroll
      for (int i = 0; i < 4; ++i) hv[i] = ftanh(ac[i] + bf2f(uva[i]));
    }
    unsigned wpk[4];
#pragma unroll
    for (int i = 0; i < 4; ++i) {
      float pv = __shfl_xor(hv[i], 1);
      wpk[i] = (unsigned)f2bf(hv[i]) | ((unsigned)f2bf(pv) << 16);
    }
    if (t >= 4) {                      // h0[t] overwrites h0[t-4]
      const int* pp = prog + (lane & 15) * 32;
      while (!__all(aload32(pp) >= t - 3)) __builtin_amdgcn_s_sleep(1);
    }
    if (cc < 2 && !(ln & 1)) {
      uint2* outs = h0ring + (t & 3) * 4096;
      const int kp = col >> 1;
#pragma unroll
      for (int i = 0; i < 4; ++i)
        astore64(outs + (cc * 4 + i) * 512 + kp,
                 ((unsigned long long)wpk[i] << 32) | (unsigned long long)(t + 1));
    }
  }
}

// layer 1: WG owns 64 cols; waves 0-3 = A (Wih1), 4-7 = B (Whh1 + output).
__device__ void rec1(const float* Wih1, const float* Whh1,
    unsigned short* feats, uint2* h0ring, uint2* h1ring, int* prog,
    int* gprog, char* smem, int wg)
{
  __builtin_amdgcn_s_setprio(1);
  const int tid = threadIdx.x, lane = tid & 63, wv = tid >> 6;
  const int ln = lane & 15, cc = lane >> 4, r = ln & 7;
  const int isB = wv >> 2;             // 0 = A-role, 1 = B-role
  const int sub = wv & 3;              // 16-col sub-tile
  const int col = wg * 64 + sub * 16 + ln;
  char* h0s = smem;                    // 16 KB
  char* h1s = smem + 16384;            // 16 KB
  float* part = (float*)(smem + 32768);  // 4 KB
  bf16x8 bw[32];
  load_bw(bw, isB ? Whh1 : Wih1, cc, col);
#pragma unroll 1
  for (int t = 0; t < T_SZ; ++t) {
    gatherN<8>(h0ring + (t & 3) * 4096 + wv * 512, (unsigned)(t + 1),
               h0s, lane, wv);
    gatherN<8>(h1ring + ((t + 3) & 3) * 4096 + wv * 512, (unsigned)t,
               h1s, lane, wv);
    __syncthreads();                   // B1: both stages complete
    f32x4 ac = mfma_k1024(isB ? h1s : h0s, bw, cc, r);
    if (!isB) *(f32x4*)(part + sub * 256 + lane * 4) = ac;
    __syncthreads();                   // B2: partials ready, stage reads done
    if (isB) {
      f32x4 pa = *(const f32x4*)(part + sub * 256 + lane * 4);
      float hv[4] = {0.f, 0.f, 0.f, 0.f};
      if (cc < 2) {
#pragma unroll
        for (int i = 0; i < 4; ++i) hv[i] = ftanh(ac[i] + pa[i]);
      }
      unsigned wpk[4];
#pragma unroll
      for (int i = 0; i < 4; ++i) {
        float pv = __shfl_xor(hv[i], 1);
        wpk[i] = (unsigned)f2bf(hv[i]) | ((unsigned)f2bf(pv) << 16);
      }
      if (cc < 2 && !(ln & 1)) {
        uint2* outs = h1ring + (t & 3) * 4096;
        const int kp = col >> 1;
#pragma unroll
        for (int i = 0; i < 4; ++i) {
          astore64(outs + (cc * 4 + i) * 512 + kp,
                   ((unsigned long long)wpk[i] << 32) | (unsigned long long)(t + 1));
          astore32((unsigned*)(feats + (size_t)(cc * 4 + i) * 524288 +
                               (size_t)t * 1024 + col), wpk[i]);
        }
      }
      if ((t & 7) == 7) {              // ordered worker gate, 8-tick gran
        asm volatile("s_waitcnt vmcnt(0)" ::: "memory");
        if (lane == 0) astore32i(gprog + (wg * 4 + sub) * 32, t + 1);
      }
    }
    if (wv == 0 && lane == 0) astore32i(prog + wg * 32, t + 1);  // L0 gate
  }
}

// ---------------- worker: 8-wave 128x128 logits tile + lse partials ---------
__device__ void gemm_tile(const unsigned short* __restrict__ A,
    const unsigned short* __restrict__ Bt, float* __restrict__ C,
    const float* __restrict__ bias, float2* __restrict__ PARTg,
    char* smem, int m0, int nb)
{
  unsigned short* As = (unsigned short*)smem;            // 128x64 (16 KB)
  unsigned short* Bs = (unsigned short*)(smem + 16384);  // 128x64 (16 KB)
  float2* lpart = (float2*)(smem + 32768);               // 8 x 64 (4 KB)
  const int n0 = nb * 128;
  const int tid = threadIdx.x;
  const int lane = tid & 63;
  const int wv = tid >> 6;             // 0..7
  const int wm = wv >> 2, wn = wv & 3; // 2 x 4 wave grid (64 x 32 each)
  const int ln = lane & 15, cc = lane >> 4;
  f32x4 acc[4][2] = {};
  const int rr = tid >> 3;             // 0..63
  const int cb = (tid & 7) << 4;

  for (int kb = 0; kb < H_DIM; kb += 64) {
    __syncthreads();
#pragma unroll
    for (int is = 0; is < 2; ++is) {
      int r = is * 64 + rr;
      int sb = cb ^ ((r & 7) << 4);
      gload_lds16((const char*)(A + (size_t)(m0 + r) * H_DIM + kb) + sb,
                  &As[(is * 64 + 8 * wv) * 64]);
    }
#pragma unroll
    for (int is = 0; is < 2; ++is) {
      int r = is * 64 + rr;
      int sb = cb ^ ((r & 7) << 4);
      gload_lds16((const char*)(Bt + (size_t)(n0 + r) * H_DIM + kb) + sb,
                  &Bs[(is * 64 + 8 * wv) * 64]);
    }
    __syncthreads();
#pragma unroll
    for (int kk = 0; kk < 2; ++kk) {
      bf16x8 af[4], bfr[2];
      const int kslot = kk * 64 + cc * 16;
#pragma unroll
      for (int mi = 0; mi < 4; ++mi) {
        int ra = wm * 64 + mi * 16 + ln;
        af[mi] = *(const bf16x8*)((const char*)As + ra * 128 + (kslot ^ ((ra & 7) << 4)));
      }
#pragma unroll
      for (int ni = 0; ni < 2; ++ni) {
        int rb = wn * 32 + ni * 16 + ln;
        bfr[ni] = *(const bf16x8*)((const char*)Bs + rb * 128 + (kslot ^ ((rb & 7) << 4)));
      }
#pragma unroll
      for (int mi = 0; mi < 4; ++mi)
#pragma unroll
        for (int ni = 0; ni < 2; ++ni)
          acc[mi][ni] = __builtin_amdgcn_mfma_f32_16x16x32_bf16(af[mi], bfr[ni], acc[mi][ni], 0, 0, 0);
    }
  }
  float bvn[2]; int ckn[2];
#pragma unroll
  for (int ni = 0; ni < 2; ++ni) {
    int col = n0 + wn * 32 + ni * 16 + ln;
    ckn[ni] = col < V_SZ;
    bvn[ni] = ckn[ni] ? bias[col] : 0.f;
  }
  float fm[16], fs[16];
#pragma unroll
  for (int mi = 0; mi < 4; ++mi) {
#pragma unroll
    for (int i = 0; i < 4; ++i) {
      float v[2];
#pragma unroll
      for (int ni = 0; ni < 2; ++ni) {
        float tv = acc[mi][ni][i] + bvn[ni];
        v[ni] = ckn[ni] ? tv : -1e30f;
        if (ckn[ni]) {
          int col = n0 + wn * 32 + ni * 16 + ln;
          __builtin_nontemporal_store(tv,
              &C[(size_t)(m0 + wm * 64 + mi * 16 + cc * 4 + i) * V_SZ + col]);
        }
      }
      float mx = fmaxf(v[0], v[1]);
#pragma unroll
      for (int m = 1; m < 16; m <<= 1) mx = fmaxf(mx, __shfl_xor(mx, m));
      float se = __expf(v[0] - mx) + __expf(v[1] - mx);
#pragma unroll
      for (int m = 1; m < 16; m <<= 1) se += __shfl_xor(se, m);
      fm[mi * 4 + i] = mx; fs[mi * 4 + i] = se;
    }
  }
  if (ln == 0) {
#pragma unroll
    for (int mi = 0; mi < 4; ++mi)
#pragma unroll
      for (int i = 0; i < 4; ++i)
        lpart[wv * 64 + mi * 16 + cc * 4 + i] =
            make_float2(fm[mi * 4 + i], fs[mi * 4 + i]);
  }
  __syncthreads();
  if (tid < 128) {                     // combine the 4 wn-waves per wm group
    const int g = tid, wmg = g >> 6, lr = g & 63;
    float2 a = lpart[(wmg * 4) * 64 + lr];
#pragma unroll
    for (int q = 1; q < 4; ++q) {
      float2 o = lpart[(wmg * 4 + q) * 64 + lr];
      float nm = fmaxf(a.x, o.x);
      a.y = a.y * __expf(a.x - nm) + o.y * __expf(o.x - nm);
      a.x = nm;
    }
    PARTg[(size_t)(m0 + g) * 393 + nb] = a;
  }
}

__device__ void worker_body(const float* Wfc, unsigned short* WfcT,
    const unsigned short* FEATS, const float* bias, float* C, float2* PARTg,
    const int* gprog, int* TCNT, int* TDONE, int* TILE, char* smem)
{
  const int tid = threadIdx.x;
  int* sT = (int*)(smem + 36864);
  // phase A: work-steal WfcT transpose chunks (32 cols x 1024 k each)
  {
    float* tt = (float*)smem;          // [32][33] f32
    const int tx = tid & 31, ty = (tid >> 5) & 15;   // 32 x 16 loaders
    const int widx = tid & 15, nrow = tid >> 4;      // 16 x 32 writers
    for (;;) {
      __syncthreads();
      if (tid == 0)
        *sT = __hip_atomic_fetch_add(TCNT, 1, __ATOMIC_RELAXED, __HIP_MEMORY_SCOPE_AGENT);
      __syncthreads();
      int ch = *sT;
      if (ch >= NCHUNK) break;
      int n0 = ch * 32;
      for (int kt = 0; kt < 32; ++kt) {
        int k0 = kt * 32;
        __syncthreads();
#pragma unroll
        for (int jj = 0; jj < 2; ++jj) {
          int k = ty + jj * 16, n = n0 + tx;
          tt[k * 33 + tx] = (n < V_SZ) ? Wfc[(size_t)(k0 + k) * V_SZ + n] : 0.f;
        }
        __syncthreads();
        {
          int n = n0 + nrow;
          float a = (n < V_SZ) ? tt[(widx * 2) * 33 + nrow] : 0.f;
          float b = (n < V_SZ) ? tt[(widx * 2 + 1) * 33 + nrow] : 0.f;
          unsigned pv = (unsigned)f2bf(a) | ((unsigned)f2bf(b) << 16);
          astore32((unsigned*)WfcT + (size_t)n * 512 + (k0 >> 1) + widx, pv);
        }
      }
      __syncthreads();
    }
    asm volatile("s_waitcnt vmcnt(0)" ::: "memory");
    __syncthreads();
    if (tid == 0)
      __hip_atomic_fetch_add(TDONE, 1, __ATOMIC_RELAXED, __HIP_MEMORY_SCOPE_AGENT);
    while (aload32(TDONE) < NWORKER) __builtin_amdgcn_s_sleep(16);
    __syncthreads();
  }
  // phase B: gated logits-tile work-stealing
  int passed = 0;
  for (;;) {
    __syncthreads();
    if (tid == 0)
      *sT = __hip_atomic_fetch_add(TILE, 1, __ATOMIC_RELAXED, __HIP_MEMORY_SCOPE_AGENT);
    __syncthreads();
    int id = *sT;
    if (id >= NTILES) break;
    int p = id / 3144, rem = id % 3144, nb = rem / 8, b = rem % 8;
    int thr = 128 * (p + 1);           // FEATS t<=thr-1 certified at gprog>=thr
    if (thr > passed) {
      const int lane = tid & 63;
      const int* gp = gprog + (lane & 63) * 32;
      while (!__all(aload32(gp) >= thr)) __builtin_amdgcn_s_sleep(32);
      passed = thr;
    }
    gemm_tile(FEATS, WfcT, C, bias, PARTg, smem, b * 512 + p * 128, nb);
  }
}

// ---------------- mega kernel ----------------------------------------------
__global__ __launch_bounds__(512) void k_mega(
    const unsigned short* __restrict__ U0, const float* __restrict__ Whh0,
    const float* __restrict__ Wih1, const float* __restrict__ Whh1,
    unsigned short* __restrict__ FEATS, const float* __restrict__ Wfc,
    unsigned short* __restrict__ WfcT, const float* __restrict__ bfc,
    float* __restrict__ logits, float2* __restrict__ PART,
    uint2* __restrict__ h0ring, uint2* __restrict__ h1ring,
    int* __restrict__ prog, int* __restrict__ gprog, int* __restrict__ cnts)
{
  __shared__ __align__(16) char smem[37376];
  const int bid = blockIdx.x;
  if (bid < 8)
    rec0(U0, Whh0, h0ring, prog, smem, bid);
  else if (bid < 24)
    rec1(Wih1, Whh1, FEATS, h0ring, h1ring, prog, gprog, smem, bid - 8);
  else
    worker_body(Wfc, WfcT, FEATS, bfc, logits, PART, gprog,
                cnts + 0, cnts + 32, cnts + 64, smem);
}

// ---------------- loss: combine per-tile partials ---------------------------
__global__ __launch_bounds__(64) void k_loss_combine(
    const float2* __restrict__ PARTg, const float* __restrict__ logits,
    const int* __restrict__ y, float* __restrict__ rowloss)
{
  const int row = blockIdx.x, l = threadIdx.x;
  float M = -1e30f, S = 0.f;
  for (int i = l; i < 393; i += 64) {
    float2 p = PARTg[(size_t)row * 393 + i];
    float nm = fmaxf(M, p.x);
    S = S * __expf(M - nm) + p.y * __expf(p.x - nm);
    M = nm;
  }
#pragma unroll
  for (int off = 32; off > 0; off >>= 1) {
    float mo = __shfl_xor(M, off), so = __shfl_xor(S, off);
    float nm = fmaxf(M, mo);
    S = S * __expf(M - nm) + so * __expf(mo - nm);
    M = nm;
  }
  if (l == 0) {
    int tgt = y[row];
    float r = 0.f;
    if (tgt >= 0) r = M + __logf(S) - logits[(size_t)row * V_SZ + tgt];
    rowloss[row] = r;
  }
}

__global__ __launch_bounds__(256) void k_loss_final(
    const float* __restrict__ rowloss, const int* __restrict__ y,
    float* __restrict__ out)
{
  const int tid = threadIdx.x;
  float s = 0.f, c = 0.f;
  for (int i = tid; i < B_SZ * T_SZ; i += 256) {
    if (y[i] != -1) { s += rowloss[i]; c += 1.f; }
  }
  for (int off = 32; off > 0; off >>= 1) { s += __shfl_xor(s, off); c += __shfl_xor(c, off); }
  __shared__ float as_[4], ac_[4];
  const int wvi = tid >> 6, lnn = tid & 63;
  if (lnn == 0) { as_[wvi] = s; ac_[wvi] = c; }
  __syncthreads();
  if (tid == 0) {
    float S = as_[0] + as_[1] + as_[2] + as_[3];
    float C = ac_[0] + ac_[1] + ac_[2] + ac_[3];
    out[0] = S / fmaxf(C, 1.f);
  }
}

// ---------------- launch ----------------------------------------------------
extern "C" void kernel_launch(void* const* d_in, const int* in_sizes, int n_in,
                              void* d_out, int out_size, void* d_ws, size_t ws_size,
                              hipStream_t stream) {
  (void)in_sizes; (void)n_in; (void)ws_size;
  const int* x = (const int*)d_in[0];
  const int* y = (const int*)d_in[1];
  const float* E = (const float*)d_in[2];
  const float* Wih0 = (const float*)d_in[3];
  const float* Whh0 = (const float*)d_in[4];
  const float* Wih1 = (const float*)d_in[5];
  const float* Whh1 = (const float*)d_in[6];
  const float* Wfc = (const float*)d_in[7];
  const float* bfc = (const float*)d_in[8];
  char* ws = (char*)d_ws;
  // workspace layout (bytes)
  unsigned short* WfcT  = (unsigned short*)(ws + 0ULL);            // 103,022,592
  unsigned short* Wih0T = (unsigned short*)(ws + 103022592ULL);    // 1,048,576
  unsigned short* XE    = (unsigned short*)(ws + 104071168ULL);    // 4,194,304
  unsigned short* U0    = (unsigned short*)(ws + 108265472ULL);    // 8,388,608
  unsigned short* FEATS = (unsigned short*)(ws + 116654080ULL);    // 8,388,608
  float2* PART          = (float2*)(ws + 125042688ULL);            // 12,877,824
  float* ROWLOSS        = (float*)(ws + 137920512ULL);             // 16,384
  uint2* H0R            = (uint2*)(ws + 137936896ULL);             // 131,072
  uint2* H1R            = (uint2*)(ws + 138067968ULL);             // 131,072
  int* PROG             = (int*)(ws + 138199040ULL);               // 2,048
  int* GPROG            = (int*)(ws + 138201088ULL);               // 8,192
  int* CNT              = (int*)(ws + 138209280ULL);               // 1,024 (zeroed)
  float* logits = (float*)d_out;
  float* lossp = logits + (size_t)(out_size - 1);

  // zero h rings (tags = 0 == "h[-1] ready") + prog/gprog/counters (incl TILE)
  hipMemsetAsync(ws + 137936896ULL, 0, 273408, stream);

  // pre: Wih0 transpose, embed, U0 GEMM
  k_transpose<<<dim3(32, 16), dim3(32, 8), 0, stream>>>(Wih0, Wih0T, 512, 1024, 1024);
  k_embed<<<4096, 128, 0, stream>>>(x, E, XE);
  k_gemm<true, false><<<dim3(8, 32), 256, 0, stream>>>(XE, Wih0T, U0, nullptr,
                                                       1024, 512, 512, 512, 1024);
  // mega: rec L0+L1 (private CUs) + worker WfcT transpose + gated logits GEMM
  k_mega<<<256, 512, 0, stream>>>(U0, Whh0, Wih1, Whh1, FEATS, Wfc, WfcT, bfc,
                                  logits, PART, H0R, H1R, PROG, GPROG, CNT);
  // loss
  k_loss_combine<<<4096, 64, 0, stream>>>(PART, logits, y, ROWLOSS);
  k_loss_final<<<1, 256, 0, stream>>>(ROWLOSS, y, lossp);
}